// Round 1
// baseline (138068.945 us; speedup 1.0000x reference)
//
#include <hip/hip_runtime.h>

#define NRES 2048
#define NBLK 256
#define FLAG_STRIDE 32   // ints -> 128B per flag line

// ---------------- W transpose: Wt[j][i] = W[i][j] ----------------
__global__ __launch_bounds__(256) void transpose_k(const float* __restrict__ W,
                                                   float* __restrict__ Wt) {
  __shared__ float tile[32][33];
  const int tx = threadIdx.x, ty = threadIdx.y;
  const int x = blockIdx.x * 32 + tx;
  const int y0 = blockIdx.y * 32;
#pragma unroll
  for (int j = ty; j < 32; j += 8)
    tile[j][tx] = W[(size_t)(y0 + j) * NRES + x];
  __syncthreads();
  const int x2 = blockIdx.y * 32 + tx;
  const int y2 = blockIdx.x * 32;
#pragma unroll
  for (int j = ty; j < 32; j += 8)
    Wt[(size_t)(y2 + j) * NRES + x2] = tile[tx][j];
}

// ---------------- uproj GEMM: U[M,N] = X[M,K] @ B[K,N], fp32 ----------------
__global__ __launch_bounds__(256) void gemm_uproj(const float* __restrict__ X,
                                                  const float* __restrict__ B,
                                                  float* __restrict__ U,
                                                  int M, int N, int K) {
  __shared__ float As[16][128];  // As[k][m]
  __shared__ float Bs[16][128];  // Bs[k][n]
  const int tid = threadIdx.x;
  const int tx = tid & 15, ty = tid >> 4;
  const int m0 = blockIdx.y * 128, n0 = blockIdx.x * 128;

  float acc[8][8];
#pragma unroll
  for (int i = 0; i < 8; i++)
#pragma unroll
    for (int j = 0; j < 8; j++) acc[i][j] = 0.f;

  const int sam = tid >> 1, sak = (tid & 1) * 8;   // A staging: row, k-half
  const int sbk = tid >> 4, sbn = (tid & 15) * 8;  // B staging: k, n-start

  for (int k0 = 0; k0 < K; k0 += 16) {
    const float* ap = X + (size_t)(m0 + sam) * K + k0 + sak;
    float4 a0 = *(const float4*)(ap);
    float4 a1 = *(const float4*)(ap + 4);
    As[sak + 0][sam] = a0.x; As[sak + 1][sam] = a0.y;
    As[sak + 2][sam] = a0.z; As[sak + 3][sam] = a0.w;
    As[sak + 4][sam] = a1.x; As[sak + 5][sam] = a1.y;
    As[sak + 6][sam] = a1.z; As[sak + 7][sam] = a1.w;
    const float* bp = B + (size_t)(k0 + sbk) * N + n0 + sbn;
    *(float4*)&Bs[sbk][sbn]     = *(const float4*)(bp);
    *(float4*)&Bs[sbk][sbn + 4] = *(const float4*)(bp + 4);
    __syncthreads();
#pragma unroll
    for (int kk = 0; kk < 16; kk++) {
      float a[8], b[8];
      *(float4*)&a[0] = *(const float4*)&As[kk][ty * 8];
      *(float4*)&a[4] = *(const float4*)&As[kk][ty * 8 + 4];
      *(float4*)&b[0] = *(const float4*)&Bs[kk][tx * 8];
      *(float4*)&b[4] = *(const float4*)&Bs[kk][tx * 8 + 4];
#pragma unroll
      for (int i = 0; i < 8; i++)
#pragma unroll
        for (int j = 0; j < 8; j++) acc[i][j] += a[i] * b[j];
    }
    __syncthreads();
  }
#pragma unroll
  for (int i = 0; i < 8; i++) {
    float* dst = U + (size_t)(m0 + ty * 8 + i) * N + n0 + tx * 8;
    *(float4*)dst       = *(float4*)&acc[i][0];
    *(float4*)(dst + 4) = *(float4*)&acc[i][4];
  }
}

// ---------------- persistent ESN scan ----------------
// 256 blocks x 256 threads. Block b owns output columns j in [8b, 8b+8).
// Wave w, half h: j = 8b + 2w + h. Sub-lane s (0..31) holds W elems
// {2s+64k, 2s+64k+1} of column j, k=0..31 (64 floats in regs).
// Sync: per-block epoch flags, one 128B line each; no atomics contention.
__global__ __launch_bounds__(256, 1) void esn_scan(const float* __restrict__ Wt,
                                                   const float* __restrict__ W,
                                                   float* __restrict__ vbuf,
                                                   int* __restrict__ flags,
                                                   float* __restrict__ UY,
                                                   int T) {
  __shared__ float v_lds[NRES];
  const int b = blockIdx.x;
  const int tid = threadIdx.x;
  const int wv = tid >> 6;
  const int lane = tid & 63;
  const int h = lane >> 5;
  const int s = lane & 31;
  const int j = b * 8 + wv * 2 + h;

  // one-time: load column j of W into registers
  float2 w2[32];
  if (Wt) {
    const float2* wrow = (const float2*)(Wt + (size_t)j * NRES);
#pragma unroll
    for (int k = 0; k < 32; ++k) w2[k] = wrow[s + 32 * k];
  } else {
#pragma unroll
    for (int k = 0; k < 32; ++k) {
      w2[k].x = W[(size_t)(2 * s + 64 * k) * NRES + j];
      w2[k].y = W[(size_t)(2 * s + 64 * k + 1) * NRES + j];
    }
  }

  float4* vl4 = (float4*)v_lds;
  for (int t = 0; t < T; ++t) {
    if (t > 0) {
      // wait for all blocks to have published v_{t-1}
      while (__hip_atomic_load(&flags[tid * FLAG_STRIDE], __ATOMIC_RELAXED,
                               __HIP_MEMORY_SCOPE_AGENT) < t) {}
      __syncthreads();
      __threadfence();  // acquire: invalidate stale caches before v loads
      const float4* vin = (const float4*)(vbuf + ((t - 1) & 1) * NRES);
      vl4[tid] = vin[tid];
      vl4[tid + 256] = vin[tid + 256];
    } else {
      float4 z = {0.f, 0.f, 0.f, 0.f};
      vl4[tid] = z;
      vl4[tid + 256] = z;
    }
    __syncthreads();

    // dot(v, W[:,j]) : 32 x float2, conflict-free (2-way = free)
    float acc = 0.f;
#pragma unroll
    for (int k = 0; k < 32; ++k) {
      float2 vv = *(const float2*)&v_lds[2 * s + 64 * k];
      acc += w2[k].x * vv.x + w2[k].y * vv.y;
    }
    // reduce across the 32 sub-lanes of each half-wave
#pragma unroll
    for (int off = 16; off >= 1; off >>= 1) acc += __shfl_xor(acc, off);

    if (s == 0) {
      const size_t idx = (size_t)t * NRES + j;
      float u = UY[idx];
      float vold = v_lds[j];
      float vnew = 0.5f * vold + 0.5f * tanhf(acc + u);
      UY[idx] = vnew;                   // states[t][j]
      vbuf[(t & 1) * NRES + j] = vnew;  // publish for step t+1
    }
    __threadfence();  // release: make v stores visible device-wide
    __syncthreads();
    if (tid == 0)
      __hip_atomic_store(&flags[b * FLAG_STRIDE], t + 1, __ATOMIC_RELAXED,
                         __HIP_MEMORY_SCOPE_AGENT);
  }
}

extern "C" void kernel_launch(void* const* d_in, const int* in_sizes, int n_in,
                              void* d_out, int out_size, void* d_ws, size_t ws_size,
                              hipStream_t stream) {
  const float* x   = (const float*)d_in[0];
  const float* Win = (const float*)d_in[1];
  const float* W   = (const float*)d_in[2];
  float* U = (float*)d_out;

  const int T = out_size / NRES;       // 4096
  const int K = in_sizes[0] / T;       // 4096 (nInput)

  char* ws = (char*)d_ws;
  float* vbuf = (float*)ws;                       // 16 KB
  int* flags  = (int*)(ws + 16 * 1024);           // 32 KB
  float* Wt = nullptr;
  const size_t wt_need = 64 * 1024 + (size_t)NRES * NRES * sizeof(float);
  if (ws_size >= wt_need) Wt = (float*)(ws + 64 * 1024);

  hipMemsetAsync(flags, 0, 32 * 1024, stream);

  if (Wt) transpose_k<<<dim3(NRES / 32, NRES / 32), dim3(32, 8), 0, stream>>>(W, Wt);

  gemm_uproj<<<dim3(NRES / 128, T / 128), 256, 0, stream>>>(x, Win, U, T, NRES, K);

  void* args[] = {(void*)&Wt, (void*)&W, (void*)&vbuf, (void*)&flags,
                  (void*)&U, (void*)&T};
  hipLaunchCooperativeKernel((const void*)esn_scan, dim3(NBLK), dim3(256), args,
                             0, stream);
}

// Round 2
// 16996.068 us; speedup vs baseline: 8.1236x; 8.1236x over previous
//
#include <hip/hip_runtime.h>

#define NRES 2048
#define NBLK 256
#define RBUF 4  // rotation depth; >=3 provably race-free, 4 for cheap &-mask

typedef unsigned long long u64;

// ---------------- W transpose: Wt[j][i] = W[i][j] ----------------
__global__ __launch_bounds__(256) void transpose_k(const float* __restrict__ W,
                                                   float* __restrict__ Wt) {
  __shared__ float tile[32][33];
  const int tx = threadIdx.x, ty = threadIdx.y;
  const int x = blockIdx.x * 32 + tx;
  const int y0 = blockIdx.y * 32;
#pragma unroll
  for (int j = ty; j < 32; j += 8)
    tile[j][tx] = W[(size_t)(y0 + j) * NRES + x];
  __syncthreads();
  const int x2 = blockIdx.y * 32 + tx;
  const int y2 = blockIdx.x * 32;
#pragma unroll
  for (int j = ty; j < 32; j += 8)
    Wt[(size_t)(y2 + j) * NRES + x2] = tile[tx][j];
}

// ---------------- uproj GEMM: U[M,N] = X[M,K] @ B[K,N], fp32 ----------------
__global__ __launch_bounds__(256) void gemm_uproj(const float* __restrict__ X,
                                                  const float* __restrict__ B,
                                                  float* __restrict__ U,
                                                  int M, int N, int K) {
  __shared__ float As[16][128];  // As[k][m]
  __shared__ float Bs[16][128];  // Bs[k][n]
  const int tid = threadIdx.x;
  const int tx = tid & 15, ty = tid >> 4;
  const int m0 = blockIdx.y * 128, n0 = blockIdx.x * 128;

  float acc[8][8];
#pragma unroll
  for (int i = 0; i < 8; i++)
#pragma unroll
    for (int j = 0; j < 8; j++) acc[i][j] = 0.f;

  const int sam = tid >> 1, sak = (tid & 1) * 8;   // A staging: row, k-half
  const int sbk = tid >> 4, sbn = (tid & 15) * 8;  // B staging: k, n-start

  for (int k0 = 0; k0 < K; k0 += 16) {
    const float* ap = X + (size_t)(m0 + sam) * K + k0 + sak;
    float4 a0 = *(const float4*)(ap);
    float4 a1 = *(const float4*)(ap + 4);
    As[sak + 0][sam] = a0.x; As[sak + 1][sam] = a0.y;
    As[sak + 2][sam] = a0.z; As[sak + 3][sam] = a0.w;
    As[sak + 4][sam] = a1.x; As[sak + 5][sam] = a1.y;
    As[sak + 6][sam] = a1.z; As[sak + 7][sam] = a1.w;
    const float* bp = B + (size_t)(k0 + sbk) * N + n0 + sbn;
    *(float4*)&Bs[sbk][sbn]     = *(const float4*)(bp);
    *(float4*)&Bs[sbk][sbn + 4] = *(const float4*)(bp + 4);
    __syncthreads();
#pragma unroll
    for (int kk = 0; kk < 16; kk++) {
      float a[8], b[8];
      *(float4*)&a[0] = *(const float4*)&As[kk][ty * 8];
      *(float4*)&a[4] = *(const float4*)&As[kk][ty * 8 + 4];
      *(float4*)&b[0] = *(const float4*)&Bs[kk][tx * 8];
      *(float4*)&b[4] = *(const float4*)&Bs[kk][tx * 8 + 4];
#pragma unroll
      for (int i = 0; i < 8; i++)
#pragma unroll
        for (int j = 0; j < 8; j++) acc[i][j] += a[i] * b[j];
    }
    __syncthreads();
  }
#pragma unroll
  for (int i = 0; i < 8; i++) {
    float* dst = U + (size_t)(m0 + ty * 8 + i) * N + n0 + tx * 8;
    *(float4*)dst       = *(float4*)&acc[i][0];
    *(float4*)(dst + 4) = *(float4*)&acc[i][4];
  }
}

// ---------------- persistent ESN scan, tagged-value sync ----------------
// 256 blocks x 256 threads, cooperative (1 block/CU). Block b owns columns
// j in [8b, 8b+8): wave wv half h -> j = 8b + 2wv + h; sub-lane s (0..31)
// holds W[:,j] elements {2s+64k, 2s+64k+1}, k=0..31 (64 floats in VGPRs).
//
// Sync: v_t[j] published as one 64-bit word {tag=t+1, f32 bits} via relaxed
// AGENT atomic store (write-through to coherence point, no cache fences).
// Consumers poll the words directly with relaxed AGENT atomic loads ->
// single L3 round trip per step. 4-buffer rotation (>=3 is race-free:
// a writer reaching step t+2 has observed all step-t+1 tags, which
// happen-after every block's step-t reads of the slot being overwritten).
__global__ __launch_bounds__(256, 1) void esn_scan(const float* __restrict__ Wt,
                                                   const float* __restrict__ W,
                                                   u64* vtag,
                                                   float* __restrict__ UY,
                                                   int T) {
  __shared__ float v_lds[NRES];
  const int b = blockIdx.x;
  const int tid = threadIdx.x;
  const int wv = tid >> 6;
  const int lane = tid & 63;
  const int h = lane >> 5;
  const int s = lane & 31;
  const int j = b * 8 + wv * 2 + h;

  // one-time: load column j of W into registers (coalesced via Wt)
  float2 w2[32];
  if (Wt) {
    const float2* wrow = (const float2*)(Wt + (size_t)j * NRES);
#pragma unroll
    for (int k = 0; k < 32; ++k) w2[k] = wrow[s + 32 * k];
  } else {
#pragma unroll
    for (int k = 0; k < 32; ++k) {
      w2[k].x = W[(size_t)(2 * s + 64 * k) * NRES + j];
      w2[k].y = W[(size_t)(2 * s + 64 * k + 1) * NRES + j];
    }
  }

  for (int t = 0; t < T; ++t) {
    if (t == 0) {
#pragma unroll
      for (int q = 0; q < 8; ++q) v_lds[tid + 256 * q] = 0.f;
    } else {
      // gather v_{t-1}: 8 tagged words/thread, all kept in flight while
      // polling (pipelined round trips, not serialized spins)
      u64* src = vtag + (size_t)((t - 1) & (RBUF - 1)) * NRES;
      unsigned pending = 0xFFu;
      while (pending) {
#pragma unroll
        for (int q = 0; q < 8; ++q) {
          if (pending & (1u << q)) {
            u64 w = __hip_atomic_load(&src[tid + 256 * q], __ATOMIC_RELAXED,
                                      __HIP_MEMORY_SCOPE_AGENT);
            if ((unsigned)(w >> 32) == (unsigned)t) {
              v_lds[tid + 256 * q] = __uint_as_float((unsigned)w);
              pending &= ~(1u << q);
            }
          }
        }
      }
    }
    // u_t load overlaps the tail of the gather (independent of v)
    const size_t idx = (size_t)t * NRES + j;
    float u = (s == 0) ? UY[idx] : 0.f;
    __syncthreads();

    // dot(v, W[:,j]) : 32 x float2, 2-way LDS aliasing (free), 2 acc chains
    float acc0 = 0.f, acc1 = 0.f;
#pragma unroll
    for (int k = 0; k < 32; k += 2) {
      float2 va = *(const float2*)&v_lds[2 * s + 64 * k];
      float2 vb = *(const float2*)&v_lds[2 * s + 64 * (k + 1)];
      acc0 += w2[k].x * va.x + w2[k].y * va.y;
      acc1 += w2[k + 1].x * vb.x + w2[k + 1].y * vb.y;
    }
    float acc = acc0 + acc1;
    // butterfly reduce across the 32 sub-lanes of each half-wave
#pragma unroll
    for (int off = 16; off >= 1; off >>= 1) acc += __shfl_xor(acc, off);

    float vold = v_lds[j];
    __syncthreads();  // protects v_lds reads from next iter's overwrites

    if (s == 0) {
      float vnew = 0.5f * vold + 0.5f * tanhf(acc + u);
      UY[idx] = vnew;  // states[t][j]
      u64 w = ((u64)(unsigned)(t + 1) << 32) | (u64)__float_as_uint(vnew);
      __hip_atomic_store(&vtag[(size_t)(t & (RBUF - 1)) * NRES + j], w,
                         __ATOMIC_RELAXED, __HIP_MEMORY_SCOPE_AGENT);
    }
  }
}

extern "C" void kernel_launch(void* const* d_in, const int* in_sizes, int n_in,
                              void* d_out, int out_size, void* d_ws, size_t ws_size,
                              hipStream_t stream) {
  const float* x   = (const float*)d_in[0];
  const float* Win = (const float*)d_in[1];
  const float* W   = (const float*)d_in[2];
  float* U = (float*)d_out;

  const int T = out_size / NRES;  // 4096
  const int K = in_sizes[0] / T;  // 4096 (nInput)

  char* ws = (char*)d_ws;
  u64* vtag = (u64*)ws;  // RBUF * NRES * 8B = 64 KB
  const size_t vtag_bytes = (size_t)RBUF * NRES * sizeof(u64);
  float* Wt = nullptr;
  const size_t wt_need = vtag_bytes + (size_t)NRES * NRES * sizeof(float);
  if (ws_size >= wt_need) Wt = (float*)(ws + vtag_bytes);

  // tags must be zeroed every launch (replays would otherwise see stale epochs)
  hipMemsetAsync(vtag, 0, vtag_bytes, stream);

  if (Wt) transpose_k<<<dim3(NRES / 32, NRES / 32), dim3(32, 8), 0, stream>>>(W, Wt);

  gemm_uproj<<<dim3(NRES / 128, T / 128), 256, 0, stream>>>(x, Win, U, T, NRES, K);

  void* args[] = {(void*)&Wt, (void*)&W, (void*)&vtag, (void*)&U, (void*)&T};
  hipLaunchCooperativeKernel((const void*)esn_scan, dim3(NBLK), dim3(256), args,
                             0, stream);
}

// Round 3
// 14741.293 us; speedup vs baseline: 9.3661x; 1.1530x over previous
//
#include <hip/hip_runtime.h>

#define NRES 2048
#define NBLK 256
#define RBUF 4  // rotation depth; >=3 provably race-free, 4 for cheap &-mask

typedef unsigned long long u64;

// ---------------- W transpose: Wt[j][i] = W[i][j] ----------------
__global__ __launch_bounds__(256) void transpose_k(const float* __restrict__ W,
                                                   float* __restrict__ Wt) {
  __shared__ float tile[32][33];
  const int tx = threadIdx.x, ty = threadIdx.y;
  const int x = blockIdx.x * 32 + tx;
  const int y0 = blockIdx.y * 32;
#pragma unroll
  for (int j = ty; j < 32; j += 8)
    tile[j][tx] = W[(size_t)(y0 + j) * NRES + x];
  __syncthreads();
  const int x2 = blockIdx.y * 32 + tx;
  const int y2 = blockIdx.x * 32;
#pragma unroll
  for (int j = ty; j < 32; j += 8)
    Wt[(size_t)(y2 + j) * NRES + x2] = tile[tx][j];
}

// ---------------- uproj GEMM: U[M,N] = X[M,K] @ B[K,N], fp32 ----------------
__global__ __launch_bounds__(256) void gemm_uproj(const float* __restrict__ X,
                                                  const float* __restrict__ B,
                                                  float* __restrict__ U,
                                                  int M, int N, int K) {
  __shared__ float As[16][128];  // As[k][m]
  __shared__ float Bs[16][128];  // Bs[k][n]
  const int tid = threadIdx.x;
  const int tx = tid & 15, ty = tid >> 4;
  const int m0 = blockIdx.y * 128, n0 = blockIdx.x * 128;

  float acc[8][8];
#pragma unroll
  for (int i = 0; i < 8; i++)
#pragma unroll
    for (int j = 0; j < 8; j++) acc[i][j] = 0.f;

  const int sam = tid >> 1, sak = (tid & 1) * 8;   // A staging: row, k-half
  const int sbk = tid >> 4, sbn = (tid & 15) * 8;  // B staging: k, n-start

  for (int k0 = 0; k0 < K; k0 += 16) {
    const float* ap = X + (size_t)(m0 + sam) * K + k0 + sak;
    float4 a0 = *(const float4*)(ap);
    float4 a1 = *(const float4*)(ap + 4);
    As[sak + 0][sam] = a0.x; As[sak + 1][sam] = a0.y;
    As[sak + 2][sam] = a0.z; As[sak + 3][sam] = a0.w;
    As[sak + 4][sam] = a1.x; As[sak + 5][sam] = a1.y;
    As[sak + 6][sam] = a1.z; As[sak + 7][sam] = a1.w;
    const float* bp = B + (size_t)(k0 + sbk) * N + n0 + sbn;
    *(float4*)&Bs[sbk][sbn]     = *(const float4*)(bp);
    *(float4*)&Bs[sbk][sbn + 4] = *(const float4*)(bp + 4);
    __syncthreads();
#pragma unroll
    for (int kk = 0; kk < 16; kk++) {
      float a[8], b[8];
      *(float4*)&a[0] = *(const float4*)&As[kk][ty * 8];
      *(float4*)&a[4] = *(const float4*)&As[kk][ty * 8 + 4];
      *(float4*)&b[0] = *(const float4*)&Bs[kk][tx * 8];
      *(float4*)&b[4] = *(const float4*)&Bs[kk][tx * 8 + 4];
#pragma unroll
      for (int i = 0; i < 8; i++)
#pragma unroll
        for (int j = 0; j < 8; j++) acc[i][j] += a[i] * b[j];
    }
    __syncthreads();
  }
#pragma unroll
  for (int i = 0; i < 8; i++) {
    float* dst = U + (size_t)(m0 + ty * 8 + i) * N + n0 + tx * 8;
    *(float4*)dst       = *(float4*)&acc[i][0];
    *(float4*)(dst + 4) = *(float4*)&acc[i][4];
  }
}

// ---------------- persistent ESN scan, tagged-value sync ----------------
// 256 blocks x 256 threads, cooperative (1 block/CU). Block b owns columns
// j in [8b, 8b+8): wave wv half h -> j = 8b + 2wv + h; sub-lane s (0..31)
// holds W[:,j] elements {2s+64k, 2s+64k+1}, k=0..31 (64 floats in VGPRs).
//
// Sync: v_t[j] published as one 64-bit word {tag=t+1, f32 bits} via relaxed
// AGENT atomic store (write-through, no cache-nuking fences). Consumers poll
// the words directly. POLL IS BRANCH-FREE: every round issues all 8 loads
// unconditionally (8 independent RTs in flight, one waitcnt) then checks
// tags — re-loading a latched word is harmless since the value is stable
// once tagged. 4-buffer rotation (>=3 race-free: a writer at step t+2 has
// observed all step-t+1 tags, which happen-after all step-t reads of the
// slot being overwritten).
__global__ __launch_bounds__(256, 1) void esn_scan(const float* __restrict__ Wt,
                                                   const float* __restrict__ W,
                                                   u64* vtag,
                                                   float* __restrict__ UY,
                                                   int T) {
  __shared__ float v_lds[NRES];
  const int b = blockIdx.x;
  const int tid = threadIdx.x;
  const int wv = tid >> 6;
  const int lane = tid & 63;
  const int h = lane >> 5;
  const int s = lane & 31;
  const int j = b * 8 + wv * 2 + h;

  // one-time: load column j of W into registers (coalesced via Wt)
  float2 w2[32];
  if (Wt) {
    const float2* wrow = (const float2*)(Wt + (size_t)j * NRES);
#pragma unroll
    for (int k = 0; k < 32; ++k) w2[k] = wrow[s + 32 * k];
  } else {
#pragma unroll
    for (int k = 0; k < 32; ++k) {
      w2[k].x = W[(size_t)(2 * s + 64 * k) * NRES + j];
      w2[k].y = W[(size_t)(2 * s + 64 * k + 1) * NRES + j];
    }
  }

  for (int t = 0; t < T; ++t) {
    // u_t load issued first: in flight during the poll wait
    const size_t idx = (size_t)t * NRES + j;
    float u = (s == 0) ? UY[idx] : 0.f;

    if (t == 0) {
#pragma unroll
      for (int q = 0; q < 8; ++q) v_lds[tid + 256 * q] = 0.f;
    } else {
      u64* src = vtag + (size_t)((t - 1) & (RBUF - 1)) * NRES;
      unsigned done = 0;
      while (done != 0xFFu) {
        u64 w[8];
#pragma unroll
        for (int q = 0; q < 8; ++q)
          w[q] = __hip_atomic_load(&src[tid + 256 * q], __ATOMIC_RELAXED,
                                   __HIP_MEMORY_SCOPE_AGENT);
#pragma unroll
        for (int q = 0; q < 8; ++q) {
          if (!(done & (1u << q)) && (unsigned)(w[q] >> 32) == (unsigned)t) {
            v_lds[tid + 256 * q] = __uint_as_float((unsigned)w[q]);
            done |= 1u << q;
          }
        }
      }
    }
    __syncthreads();

    // dot(v, W[:,j]) : 32 x float2, 2-way LDS aliasing (free), 2 acc chains
    float acc0 = 0.f, acc1 = 0.f;
#pragma unroll
    for (int k = 0; k < 32; k += 2) {
      float2 va = *(const float2*)&v_lds[2 * s + 64 * k];
      float2 vb = *(const float2*)&v_lds[2 * s + 64 * (k + 1)];
      acc0 += w2[k].x * va.x + w2[k].y * va.y;
      acc1 += w2[k + 1].x * vb.x + w2[k + 1].y * vb.y;
    }
    float acc = acc0 + acc1;
    // butterfly reduce across the 32 sub-lanes of each half-wave
#pragma unroll
    for (int off = 16; off >= 1; off >>= 1) acc += __shfl_xor(acc, off);

    float vold = v_lds[j];
    __syncthreads();  // protects v_lds reads from next iter's overwrites

    if (s == 0) {
      float vnew = 0.5f * vold + 0.5f * tanhf(acc + u);
      UY[idx] = vnew;  // states[t][j]
      u64 w = ((u64)(unsigned)(t + 1) << 32) | (u64)__float_as_uint(vnew);
      __hip_atomic_store(&vtag[(size_t)(t & (RBUF - 1)) * NRES + j], w,
                         __ATOMIC_RELAXED, __HIP_MEMORY_SCOPE_AGENT);
    }
  }
}

extern "C" void kernel_launch(void* const* d_in, const int* in_sizes, int n_in,
                              void* d_out, int out_size, void* d_ws, size_t ws_size,
                              hipStream_t stream) {
  const float* x   = (const float*)d_in[0];
  const float* Win = (const float*)d_in[1];
  const float* W   = (const float*)d_in[2];
  float* U = (float*)d_out;

  const int T = out_size / NRES;  // 4096
  const int K = in_sizes[0] / T;  // 4096 (nInput)

  char* ws = (char*)d_ws;
  u64* vtag = (u64*)ws;  // RBUF * NRES * 8B = 64 KB
  const size_t vtag_bytes = (size_t)RBUF * NRES * sizeof(u64);
  float* Wt = nullptr;
  const size_t wt_need = vtag_bytes + (size_t)NRES * NRES * sizeof(float);
  if (ws_size >= wt_need) Wt = (float*)(ws + vtag_bytes);

  // tags must be zeroed every launch (replays would otherwise see stale epochs)
  hipMemsetAsync(vtag, 0, vtag_bytes, stream);

  if (Wt) transpose_k<<<dim3(NRES / 32, NRES / 32), dim3(32, 8), 0, stream>>>(W, Wt);

  gemm_uproj<<<dim3(NRES / 128, T / 128), 256, 0, stream>>>(x, Win, U, T, NRES, K);

  void* args[] = {(void*)&Wt, (void*)&W, (void*)&vtag, (void*)&U, (void*)&T};
  hipLaunchCooperativeKernel((const void*)esn_scan, dim3(NBLK), dim3(256), args,
                             0, stream);
}

// Round 4
// 14293.674 us; speedup vs baseline: 9.6594x; 1.0313x over previous
//
#include <hip/hip_runtime.h>

#define NRES 2048
#define NBLK 256
#define RBUF 4  // rotation depth; >=3 provably race-free, 4 for cheap &-mask

typedef unsigned long long u64;

// ---------------- W transpose: Wt[j][i] = W[i][j] ----------------
__global__ __launch_bounds__(256) void transpose_k(const float* __restrict__ W,
                                                   float* __restrict__ Wt) {
  __shared__ float tile[32][33];
  const int tx = threadIdx.x, ty = threadIdx.y;
  const int x = blockIdx.x * 32 + tx;
  const int y0 = blockIdx.y * 32;
#pragma unroll
  for (int j = ty; j < 32; j += 8)
    tile[j][tx] = W[(size_t)(y0 + j) * NRES + x];
  __syncthreads();
  const int x2 = blockIdx.y * 32 + tx;
  const int y2 = blockIdx.x * 32;
#pragma unroll
  for (int j = ty; j < 32; j += 8)
    Wt[(size_t)(y2 + j) * NRES + x2] = tile[tx][j];
}

// ---------------- uproj GEMM: U[M,N] = X[M,K] @ B[K,N], fp32 ----------------
__global__ __launch_bounds__(256) void gemm_uproj(const float* __restrict__ X,
                                                  const float* __restrict__ B,
                                                  float* __restrict__ U,
                                                  int M, int N, int K) {
  __shared__ float As[16][128];  // As[k][m]
  __shared__ float Bs[16][128];  // Bs[k][n]
  const int tid = threadIdx.x;
  const int tx = tid & 15, ty = tid >> 4;
  const int m0 = blockIdx.y * 128, n0 = blockIdx.x * 128;

  float acc[8][8];
#pragma unroll
  for (int i = 0; i < 8; i++)
#pragma unroll
    for (int j = 0; j < 8; j++) acc[i][j] = 0.f;

  const int sam = tid >> 1, sak = (tid & 1) * 8;   // A staging: row, k-half
  const int sbk = tid >> 4, sbn = (tid & 15) * 8;  // B staging: k, n-start

  for (int k0 = 0; k0 < K; k0 += 16) {
    const float* ap = X + (size_t)(m0 + sam) * K + k0 + sak;
    float4 a0 = *(const float4*)(ap);
    float4 a1 = *(const float4*)(ap + 4);
    As[sak + 0][sam] = a0.x; As[sak + 1][sam] = a0.y;
    As[sak + 2][sam] = a0.z; As[sak + 3][sam] = a0.w;
    As[sak + 4][sam] = a1.x; As[sak + 5][sam] = a1.y;
    As[sak + 6][sam] = a1.z; As[sak + 7][sam] = a1.w;
    const float* bp = B + (size_t)(k0 + sbk) * N + n0 + sbn;
    *(float4*)&Bs[sbk][sbn]     = *(const float4*)(bp);
    *(float4*)&Bs[sbk][sbn + 4] = *(const float4*)(bp + 4);
    __syncthreads();
#pragma unroll
    for (int kk = 0; kk < 16; kk++) {
      float a[8], b[8];
      *(float4*)&a[0] = *(const float4*)&As[kk][ty * 8];
      *(float4*)&a[4] = *(const float4*)&As[kk][ty * 8 + 4];
      *(float4*)&b[0] = *(const float4*)&Bs[kk][tx * 8];
      *(float4*)&b[4] = *(const float4*)&Bs[kk][tx * 8 + 4];
#pragma unroll
      for (int i = 0; i < 8; i++)
#pragma unroll
        for (int j = 0; j < 8; j++) acc[i][j] += a[i] * b[j];
    }
    __syncthreads();
  }
#pragma unroll
  for (int i = 0; i < 8; i++) {
    float* dst = U + (size_t)(m0 + ty * 8 + i) * N + n0 + tx * 8;
    *(float4*)dst       = *(float4*)&acc[i][0];
    *(float4*)(dst + 4) = *(float4*)&acc[i][4];
  }
}

// ---------------- persistent ESN scan, tagged-value sync ----------------
// 256 blocks x 256 threads, cooperative (1 block/CU). Block b owns columns
// j in [8b, 8b+8): wave wv half h -> j = 8b + 2wv + h; sub-lane s (0..31)
// holds W[:,j] elements {2s+64k, 2s+64k+1}, k=0..31 (64 floats in VGPRs).
//
// Sync: v_t[j] published as one 64-bit word {tag=t+1, f32 bits} via a
// fire-and-forget global_atomic_swap (RMW executes at the coherence point —
// no lazy write-combine drain, unlike a relaxed store). Consumers poll the
// words with relaxed AGENT loads, branch-free (8 loads in flight / round).
// v_lds is double-buffered so ONE __syncthreads per step suffices:
// a thread filling buf (t&1) at step t has passed its step-(t-1) barrier,
// which happens-after every thread's step-(t-2) reads of that buffer.
// v_old[j] lives in a register on the publishing lane (s==0) — no LDS
// re-read, no second barrier. tanh via exact identity 1 - 2/(e^2x + 1).
__global__ __launch_bounds__(256, 1) void esn_scan(const float* __restrict__ Wt,
                                                   const float* __restrict__ W,
                                                   u64* vtag,
                                                   float* __restrict__ UY,
                                                   int T) {
  __shared__ float v_lds[2][NRES];
  const int b = blockIdx.x;
  const int tid = threadIdx.x;
  const int wv = tid >> 6;
  const int lane = tid & 63;
  const int h = lane >> 5;
  const int s = lane & 31;
  const int j = b * 8 + wv * 2 + h;

  // one-time: load column j of W into registers (coalesced via Wt)
  float2 w2[32];
  if (Wt) {
    const float2* wrow = (const float2*)(Wt + (size_t)j * NRES);
#pragma unroll
    for (int k = 0; k < 32; ++k) w2[k] = wrow[s + 32 * k];
  } else {
#pragma unroll
    for (int k = 0; k < 32; ++k) {
      w2[k].x = W[(size_t)(2 * s + 64 * k) * NRES + j];
      w2[k].y = W[(size_t)(2 * s + 64 * k + 1) * NRES + j];
    }
  }

  float vold = 0.f;  // v_{t-1}[j], live on s==0 lanes only

#pragma unroll
  for (int q = 0; q < 8; ++q) v_lds[0][tid + 256 * q] = 0.f;
  __syncthreads();

  for (int t = 0; t < T; ++t) {
    const int buf = t & 1;
    // u_t load issued first: in flight during the poll wait
    const size_t idx = (size_t)t * NRES + j;
    float u = (s == 0) ? UY[idx] : 0.f;

    if (t > 0) {
      u64* src = vtag + (size_t)((t - 1) & (RBUF - 1)) * NRES;
      unsigned done = 0;
      while (done != 0xFFu) {
        u64 w[8];
#pragma unroll
        for (int q = 0; q < 8; ++q)
          w[q] = __hip_atomic_load(&src[tid + 256 * q], __ATOMIC_RELAXED,
                                   __HIP_MEMORY_SCOPE_AGENT);
#pragma unroll
        for (int q = 0; q < 8; ++q) {
          if (!(done & (1u << q)) && (unsigned)(w[q] >> 32) == (unsigned)t) {
            v_lds[buf][tid + 256 * q] = __uint_as_float((unsigned)w[q]);
            done |= 1u << q;
          }
        }
      }
      __syncthreads();
    }

    // dot(v, W[:,j]) : 32 x float2, 2-way LDS aliasing (free), 2 acc chains
    float acc0 = 0.f, acc1 = 0.f;
#pragma unroll
    for (int k = 0; k < 32; k += 2) {
      float2 va = *(const float2*)&v_lds[buf][2 * s + 64 * k];
      float2 vb = *(const float2*)&v_lds[buf][2 * s + 64 * (k + 1)];
      acc0 += w2[k].x * va.x + w2[k].y * va.y;
      acc1 += w2[k + 1].x * vb.x + w2[k + 1].y * vb.y;
    }
    float acc = acc0 + acc1;
    // butterfly reduce across the 32 sub-lanes of each half-wave
#pragma unroll
    for (int off = 16; off >= 1; off >>= 1) acc += __shfl_xor(acc, off);

    if (s == 0) {
      float xx = acc + u;
      float e = __expf(2.f * xx);          // v_exp_f32 path
      float th = 1.f - 2.f / (e + 1.f);    // == tanh(xx) exactly
      float vnew = 0.5f * vold + 0.5f * th;
      vold = vnew;
      UY[idx] = vnew;  // states[t][j]
      u64 w = ((u64)(unsigned)(t + 1) << 32) | (u64)__float_as_uint(vnew);
      // fire-and-forget swap: RMW performed at the coherence point,
      // forces prompt cross-XCD visibility (vs lazily-drained store)
      (void)__hip_atomic_exchange(&vtag[(size_t)(t & (RBUF - 1)) * NRES + j],
                                  w, __ATOMIC_RELAXED,
                                  __HIP_MEMORY_SCOPE_AGENT);
    }
  }
}

extern "C" void kernel_launch(void* const* d_in, const int* in_sizes, int n_in,
                              void* d_out, int out_size, void* d_ws, size_t ws_size,
                              hipStream_t stream) {
  const float* x   = (const float*)d_in[0];
  const float* Win = (const float*)d_in[1];
  const float* W   = (const float*)d_in[2];
  float* U = (float*)d_out;

  const int T = out_size / NRES;  // 4096
  const int K = in_sizes[0] / T;  // 4096 (nInput)

  char* ws = (char*)d_ws;
  u64* vtag = (u64*)ws;  // RBUF * NRES * 8B = 64 KB
  const size_t vtag_bytes = (size_t)RBUF * NRES * sizeof(u64);
  float* Wt = nullptr;
  const size_t wt_need = vtag_bytes + (size_t)NRES * NRES * sizeof(float);
  if (ws_size >= wt_need) Wt = (float*)(ws + vtag_bytes);

  // tags must be zeroed every launch (replays would otherwise see stale epochs)
  hipMemsetAsync(vtag, 0, vtag_bytes, stream);

  if (Wt) transpose_k<<<dim3(NRES / 32, NRES / 32), dim3(32, 8), 0, stream>>>(W, Wt);

  gemm_uproj<<<dim3(NRES / 128, T / 128), 256, 0, stream>>>(x, Win, U, T, NRES, K);

  void* args[] = {(void*)&Wt, (void*)&W, (void*)&vtag, (void*)&U, (void*)&T};
  hipLaunchCooperativeKernel((const void*)esn_scan, dim3(NBLK), dim3(256), args,
                             0, stream);
}